// Round 4
// baseline (84.859 us; speedup 1.0000x reference)
//
#include <hip/hip_runtime.h>

#define B_N 8
#define A_N 100000
#define M_N 64
#define ANCH 4
#define TPB 256
#define GX ((A_N + TPB * ANCH - 1) / (TPB * ANCH))   // 98 blocks per batch

// d_ws layout: [0, B_N*M_N) float4 transformed annotations {x1,x2,len,0},
// then ws_num[B_N*GX], ws_cnt[B_N*GX].

__global__ __launch_bounds__(512) void rl_prep(
    const float* __restrict__ annotations,   // (B, M, 3)
    float4* __restrict__ ann_t)
{
    const int t = threadIdx.x;               // 512 == B_N * M_N
    const float* p = annotations + t * 3;
    float x1 = p[0], x2 = p[1], lab = p[2];
    if (lab == -1.0f) { x1 = 1e30f; x2 = 1e30f; }
    // invalid => iw extremely negative, len = 0 => never wins once any
    // overlap exists; if it "wins" the running best is still < 0.5 gate.
    ann_t[t] = make_float4(x1, x2, x2 - x1, 0.0f);
}

__global__ __launch_bounds__(TPB) void rl_main(
    const float* __restrict__ regressions,   // (B, A, 2)
    const float* __restrict__ anchors,       // (1, A, 2)
    const float4* __restrict__ ann_t,        // (B*M) transformed
    float* __restrict__ ws_num, float* __restrict__ ws_cnt)
{
    __shared__ float4 ann_lds[M_N];          // epilogue random access only
    const int b = blockIdx.y;
    const int tid = threadIdx.x;

    if (tid < M_N) ann_lds[tid] = ann_t[b * M_N + tid];
    // NOTE: no __syncthreads here — hot loop reads only scalar/global data;
    // sync is deferred to just before the epilogue's ann_lds[idx] use.

    const int abase = blockIdx.x * (TPB * ANCH) + tid;

    float a0[ANCH], a1[ANCH], aw[ANCH];
    // two independent chains per anchor: half 0 (m<32), half 1 (m>=32)
    float iwb0[ANCH], Sb0[ANCH], iwb1[ANCH], Sb1[ANCH];
    int idx0[ANCH], idx1[ANCH];
    bool act[ANCH];
    #pragma unroll
    for (int k = 0; k < ANCH; ++k) {
        int a = abase + k * TPB;
        act[k] = (a < A_N);
        a = act[k] ? a : (A_N - 1);                  // clamped, always valid
        const float2 anc = ((const float2*)anchors)[a];
        a0[k] = anc.x; a1[k] = anc.y; aw[k] = anc.y - anc.x;
        iwb0[k] = -1.0f; Sb0[k] = 1.0f; idx0[k] = 0; // encodes iou = -1
        iwb1[k] = -1.0f; Sb1[k] = 1.0f; idx1[k] = 32;
    }

    // Hot loop: wave-uniform reads -> s_load; no LDS/VMEM in loop.
    // iou = iw/(S-iw), S = aw+len, monotone in iw/S -> cross-mul compare.
    // No clamp on iw: negative-iw "winners" only occur while best iou < 0
    // and always fail the 0.5 gate, so the contribution is unchanged.
    // 8 chains/thread (4 anchors x 2 halves) for ILP; pair tournament
    // inside each half keeps the carried chain at 8 levels.
    const float4* annb = ann_t + b * M_N;
    #pragma unroll 4
    for (int p = 0; p < M_N / 4; ++p) {
        const int m = 2 * p;
        const float4 t0 = annb[m];
        const float4 t1 = annb[m + 1];
        const float4 u0 = annb[m + 32];
        const float4 u1 = annb[m + 33];
        #pragma unroll
        for (int k = 0; k < ANCH; ++k) {
            // half 0
            {
                const float iw0 = fminf(a1[k], t0.y) - fmaxf(a0[k], t0.x);
                const float iw1 = fminf(a1[k], t1.y) - fmaxf(a0[k], t1.x);
                const float S0 = aw[k] + t0.z;
                const float S1 = aw[k] + t1.z;
                const bool w1 = iw1 * S0 > iw0 * S1;          // tie -> m
                const float iww = w1 ? iw1 : iw0;
                const float Sw  = w1 ? S1  : S0;
                const int   mw  = w1 ? m + 1 : m;
                const bool bet = iww * Sb0[k] > iwb0[k] * Sw; // tie -> best
                iwb0[k] = bet ? iww : iwb0[k];
                Sb0[k]  = bet ? Sw  : Sb0[k];
                idx0[k] = bet ? mw  : idx0[k];
            }
            // half 1
            {
                const float iw0 = fminf(a1[k], u0.y) - fmaxf(a0[k], u0.x);
                const float iw1 = fminf(a1[k], u1.y) - fmaxf(a0[k], u1.x);
                const float S0 = aw[k] + u0.z;
                const float S1 = aw[k] + u1.z;
                const bool w1 = iw1 * S0 > iw0 * S1;
                const float iww = w1 ? iw1 : iw0;
                const float Sw  = w1 ? S1  : S0;
                const int   mw  = w1 ? m + 33 : m + 32;
                const bool bet = iww * Sb1[k] > iwb1[k] * Sw;
                iwb1[k] = bet ? iww : iwb1[k];
                Sb1[k]  = bet ? Sw  : Sb1[k];
                idx1[k] = bet ? mw  : idx1[k];
            }
        }
    }

    __syncthreads();   // ann_lds ready for epilogue random access

    float lsum = 0.0f, lpos = 0.0f;
    #pragma unroll
    for (int k = 0; k < ANCH; ++k) {
        // merge halves: strict '>' keeps half-0 on ties (lower index)
        const bool h1 = iwb1[k] * Sb0[k] > iwb0[k] * Sb1[k];
        const float iwb = h1 ? iwb1[k] : iwb0[k];
        const float Sb  = h1 ? Sb1[k]  : Sb0[k];
        const int   idx = h1 ? idx1[k] : idx0[k];
        // exact gate, reference rounding order
        const float ua  = fmaxf(Sb - iwb, 1e-8f);
        const float iou = iwb / ua;
        if (act[k] && iou >= 0.5f) {
            const float4 g = ann_lds[idx];
            const float gw0 = g.z;
            const float gcx = g.x + 0.5f * gw0;
            const float gw  = fmaxf(gw0, 1.0f);
            const float acx = a0[k] + 0.5f * aw[k];
            const float tdx = ((gcx - acx) / aw[k]) / 0.1f;
            const float tdw = logf(gw / aw[k]) / 0.2f;
            const float2 rg =
                ((const float2*)regressions)[(size_t)b * A_N + abase + k * TPB];
            const float d0 = fabsf(tdx - rg.x);
            const float d1 = fabsf(tdw - rg.y);
            const float inv9 = 1.0f / 9.0f;
            const float s0 = (d0 <= inv9) ? 4.5f * d0 * d0 : d0 - 0.5f / 9.0f;
            const float s1 = (d1 <= inv9) ? 4.5f * d1 * d1 : d1 - 0.5f / 9.0f;
            lsum += s0 + s1;
            lpos += 1.0f;
        }
    }

    for (int o = 32; o > 0; o >>= 1) {
        lsum += __shfl_down(lsum, o, 64);
        lpos += __shfl_down(lpos, o, 64);
    }
    __shared__ float wsum[TPB / 64], wpos[TPB / 64];
    const int wid  = tid >> 6;
    const int lane = tid & 63;
    if (lane == 0) { wsum[wid] = lsum; wpos[wid] = lpos; }
    __syncthreads();
    if (tid == 0) {
        float s = 0.0f, p = 0.0f;
        #pragma unroll
        for (int w = 0; w < TPB / 64; ++w) { s += wsum[w]; p += wpos[w]; }
        const int slot = b * GX + blockIdx.x;
        ws_num[slot] = s;
        ws_cnt[slot] = p;
    }
}

__global__ __launch_bounds__(512) void rl_final(
    const float* __restrict__ ws_num,
    const float* __restrict__ ws_cnt,
    float* __restrict__ out)
{
    const int wid  = threadIdx.x >> 6;   // wave w handles batch w
    const int lane = threadIdx.x & 63;
    float s = 0.0f, c = 0.0f;
    for (int i = lane; i < GX; i += 64) {
        s += ws_num[wid * GX + i];
        c += ws_cnt[wid * GX + i];
    }
    for (int o = 32; o > 0; o >>= 1) {
        s += __shfl_down(s, o, 64);
        c += __shfl_down(c, o, 64);
    }
    __shared__ float pb[B_N];
    if (lane == 0) {
        const float cnt = 2.0f * c;
        pb[wid] = (cnt > 0.0f) ? s / fmaxf(cnt, 1.0f) : 0.0f;
    }
    __syncthreads();
    if (threadIdx.x == 0) {
        float acc = 0.0f;
        #pragma unroll
        for (int i = 0; i < B_N; ++i) acc += pb[i];
        out[0] = acc * (1.0f / (float)B_N);
    }
}

extern "C" void kernel_launch(void* const* d_in, const int* in_sizes, int n_in,
                              void* d_out, int out_size, void* d_ws, size_t ws_size,
                              hipStream_t stream) {
    const float* regressions = (const float*)d_in[0];
    const float* anchors     = (const float*)d_in[1];
    const float* annotations = (const float*)d_in[2];
    float* out = (float*)d_out;

    float4* ann_t = (float4*)d_ws;                       // [B_N*M_N]
    float*  ws_num = (float*)(ann_t + B_N * M_N);        // [B_N*GX]
    float*  ws_cnt = ws_num + B_N * GX;                  // [B_N*GX]

    rl_prep<<<1, 512, 0, stream>>>(annotations, ann_t);
    dim3 grid(GX, B_N);
    rl_main<<<grid, TPB, 0, stream>>>(regressions, anchors, ann_t,
                                      ws_num, ws_cnt);
    rl_final<<<1, 512, 0, stream>>>(ws_num, ws_cnt, out);
}